// Round 3
// baseline (351.856 us; speedup 1.0000x reference)
//
#include <hip/hip_runtime.h>
#include <stdint.h>

// out[b,o,m] = sum_i in[b,i,m] * w[i,o,m]  (complex, fp32)
// B=32, Ci=Co=128, M=64*65=4160. One float2 per complex element.
//
// Block: MPB=4 modes, full 32b x 128o. 512 thr = [worker s:7][mode ml:2];
// worker tile 8b x 4o (64 VGPR acc, v_pk_fma_f32 complex MACs).
// Staging: global_load_lds dwordx4 (16B DMA, no VGPR round-trip), double-
// buffered LDS (2 x 20KB), 2-phase pipeline: issue chunk c+1 DMA, compute
// chunk c, one syncthreads (its vmcnt(0) is the drain). W tile XOR-swizzled
// (both sides: pre-swizzled global src + swizzled ds_read) to kill the
// 16-way bank conflict a linear [o][ml] layout would give.

typedef float f2 __attribute__((ext_vector_type(2)));

#define NB 32
#define CI 128
#define CO 128
#define MODES 4160
#define MPB 4
#define KC 4
#define NCHUNK (CI / KC)
#define ABUF_F2 (KC * NB * MPB)       // 512 f2  = 4 KB
#define WBUF_F2 (KC * CO * MPB)       // 2048 f2 = 16 KB
#define BUF_F2  (ABUF_F2 + WBUF_F2)   // 20 KB per buffer

// acc.lo += a.lo*w.lo - a.hi*w.hi ; acc.hi += a.lo*w.hi + a.hi*w.lo
#define CFMA(acc, av, wv)                                                      \
  asm("v_pk_fma_f32 %0, %1, %2, %0 op_sel:[0,0,0] op_sel_hi:[0,1,1]"           \
      : "+v"(acc) : "v"(av), "v"(wv));                                         \
  asm("v_pk_fma_f32 %0, %1, %2, %0 op_sel:[1,1,0] op_sel_hi:[1,0,1] "          \
      "neg_lo:[1,0,0]"                                                         \
      : "+v"(acc) : "v"(av), "v"(wv));

__device__ __forceinline__ void gload16(const f2* g, f2* l) {
    __builtin_amdgcn_global_load_lds(
        (const __attribute__((address_space(1))) uint32_t*)g,
        (__attribute__((address_space(3))) uint32_t*)l, 16, 0, 0);
}

// Stage one K-chunk (KC=4) into dst. Linear LDS order = DMA lane order.
// A region: unit j (0..255):  kk=j>>6, b=(j>>1)&31, ml0=(j&1)*2   (no swizzle)
// W region: unit j (0..1023): phys = j*16; logical o recovered with the
//   inverse of  phys = (kk*4096 + o*32 + ml*8) ^ (((o>>2)&3)<<5):
//   o[6:2]=jj>>3, o[1:0]=((jj>>1)&3)^((jj>>3)&3), ml0=(jj&1)*2.
__device__ __forceinline__ void stage_chunk(const f2* __restrict__ Ig,
                                            const f2* __restrict__ Wl,
                                            f2* dst, int t, int m0, int k0) {
    if (t < 256) {   // wave-uniform branch (waves 0-3)
        const int kk = t >> 6, b = (t >> 1) & 31, ml0 = (t & 1) << 1;
        gload16(Ig + (size_t)(b * CI + k0 + kk) * MODES + m0 + ml0,
                dst + t * 2);
    }
#pragma unroll
    for (int p = 0; p < 2; ++p) {
        const int j  = p * 512 + t;
        const int jj = j & 255, kk = j >> 8;
        const int ohi = jj >> 3;
        const int o   = (ohi << 2) | (((jj >> 1) & 3) ^ (ohi & 3));
        const int ml0 = (jj & 1) << 1;
        gload16(Wl + (size_t)((k0 + kk) * CO + o) * MODES + m0 + ml0,
                dst + ABUF_F2 + j * 2);
    }
}

__global__ __launch_bounds__(512, 4)
void cmul2d_kernel(const f2* __restrict__ Ig,
                   const f2* __restrict__ Wl,
                   f2* __restrict__ Og) {
    __shared__ f2 lds[2 * BUF_F2];   // 40 KB

    const int t = threadIdx.x;

    // pair-preserving XCD swizzle (mode-quad pairs of one 64B line -> same L2)
    const int bid  = blockIdx.x;
    const int x    = bid & 7;
    const int half = (bid >> 3) & 1;
    const int kq   = bid >> 4;
    const int m0   = (((kq << 3) + x) * 2 + half) * MPB;

    const int ml = t & 3;
    const int s  = t >> 2;
    const int so = s & 31;
    const int sb = s >> 5;

    // swizzled effective o-rows for the W ds_read side (matches staging XOR)
    int oe[4];
#pragma unroll
    for (int q = 0; q < 4; ++q)
        oe[q] = ((so << 2) | q) ^ (so & 3);

    f2 acc[8][4];
#pragma unroll
    for (int r = 0; r < 8; ++r)
#pragma unroll
        for (int q = 0; q < 4; ++q) acc[r][q] = (f2)(0.0f);

    stage_chunk(Ig, Wl, lds, t, m0, 0);
    __syncthreads();   // vmcnt(0) drain + barrier: buffer 0 ready

#pragma unroll 1
    for (int c = 0; c < NCHUNK; ++c) {
        if (c + 1 < NCHUNK)   // issue next chunk's DMA; flies under compute
            stage_chunk(Ig, Wl, lds + ((c + 1) & 1) * BUF_F2, t, m0,
                        (c + 1) * KC);

        const f2* Ab = lds + (c & 1) * BUF_F2;
        const f2* Wb = Ab + ABUF_F2;
#pragma unroll
        for (int kk = 0; kk < KC; ++kk) {
            f2 a[8], w[4];
#pragma unroll
            for (int r = 0; r < 8; ++r)
                a[r] = Ab[kk * (NB * MPB) + (sb * 8 + r) * MPB + ml];
#pragma unroll
            for (int q = 0; q < 4; ++q)
                w[q] = Wb[kk * (CO * MPB) + oe[q] * MPB + ml];
#pragma unroll
            for (int r = 0; r < 8; ++r)
#pragma unroll
                for (int q = 0; q < 4; ++q) {
                    CFMA(acc[r][q], a[r], w[q]);
                }
        }
        __syncthreads();   // drains this iter's DMA (vmcnt 0) + LDS reads
    }

    // epilogue: one f2 store per element; 4-lane mode groups = 32B segments
#pragma unroll
    for (int r = 0; r < 8; ++r) {
        const int b = sb * 8 + r;
#pragma unroll
        for (int q = 0; q < 4; ++q) {
            const int o = so * 4 + q;
            Og[(size_t)(b * CO + o) * MODES + m0 + ml] = acc[r][q];
        }
    }
}

extern "C" void kernel_launch(void* const* d_in, const int* in_sizes, int n_in,
                              void* d_out, int out_size, void* d_ws, size_t ws_size,
                              hipStream_t stream) {
    const f2* I = (const f2*)d_in[0];
    const f2* W = (const f2*)d_in[1];
    f2* O = (f2*)d_out;
    dim3 grid(MODES / MPB);   // 1040
    dim3 block(512);
    cmul2d_kernel<<<grid, block, 0, stream>>>(I, W, O);
}